// Round 3
// baseline (413.965 us; speedup 1.0000x reference)
//
#include <hip/hip_runtime.h>
#include <math.h>

typedef __bf16 bf16;
typedef __attribute__((ext_vector_type(8))) __bf16 bf16x8;
typedef __attribute__((ext_vector_type(4))) float f32x4;

#define CDIV(a,b) (((a)+(b)-1)/(b))

// ---------------------------------------------------------------------------
// Problem constants: B=16, L=1024, U=512, H=2. M = B*L = 16384.
// All in/out tensors are fp32 (per reference source). bf16 is internal only
// (MFMA GEMM operands). R2's NaN proved inputs are NOT bf16; R1's bounded
// garbage proved compute was right but d_out must be written as fp32.
// ---------------------------------------------------------------------------

struct GemmArgs {
  const bf16* A; const bf16* B; bf16* C;
  int K, lda, ldb, ldc;
  long long Ab, Bb, Cb;          // batch strides in elements
  const float* bias;             // EPI 0 / 3
  const float* s1; const float* s2; const float* abp; // EPI 1
  int L;
};

// NT GEMM: C[M,N] = A[M,K] @ Bt[N,K]^T, all bf16, fp32 accum.
// Block tile 128x128, BK=32, 256 threads = 4 waves in 2x2, each wave 64x64
// via 4x4 mfma_f32_16x16x32_bf16.
// LDS layout "chunked": As[kchunk(4)][row(128)][8 bf16] -> 16B-aligned
// ds_read_b128 fragments.
template<int EPI>
__global__ __launch_bounds__(256, 2)
void gemm_nt(GemmArgs g) {
  __shared__ bf16 As[4 * 128 * 8];
  __shared__ bf16 Bs[4 * 128 * 8];
  const int tid = threadIdx.x;
  const int bx = blockIdx.x, by = blockIdx.y, bz = blockIdx.z;
  const bf16* Ag = g.A + (long long)bz * g.Ab + (long long)(by * 128) * g.lda;
  const bf16* Bg = g.B + (long long)bz * g.Bb + (long long)(bx * 128) * g.ldb;
  const int wid = tid >> 6, lane = tid & 63;
  const int wm = (wid >> 1) << 6;      // wave row offset 0/64
  const int wn = (wid & 1) << 6;       // wave col offset 0/64
  const int lr = lane & 15, lq = lane >> 4;

  f32x4 acc[4][4];
#pragma unroll
  for (int i = 0; i < 4; i++)
#pragma unroll
    for (int j = 0; j < 4; j++) acc[i][j] = f32x4{0.f, 0.f, 0.f, 0.f};

  const int r0 = tid >> 2;             // staging row 0..63 (+64 second half)
  const int kcI = tid & 3;             // k-chunk index 0..3
  const int kc = kcI * 8;              // k offset within BK

  for (int k0 = 0; k0 < g.K; k0 += 32) {
    // issue global loads before the barrier so they overlap prior compute
    bf16x8 a0 = *(const bf16x8*)(Ag + (long long)r0 * g.lda + k0 + kc);
    bf16x8 a1 = *(const bf16x8*)(Ag + (long long)(r0 + 64) * g.lda + k0 + kc);
    bf16x8 b0 = *(const bf16x8*)(Bg + (long long)r0 * g.ldb + k0 + kc);
    bf16x8 b1 = *(const bf16x8*)(Bg + (long long)(r0 + 64) * g.ldb + k0 + kc);
    __syncthreads();
    *(bf16x8*)(&As[(kcI * 128 + r0) * 8]) = a0;
    *(bf16x8*)(&As[(kcI * 128 + r0 + 64) * 8]) = a1;
    *(bf16x8*)(&Bs[(kcI * 128 + r0) * 8]) = b0;
    *(bf16x8*)(&Bs[(kcI * 128 + r0 + 64) * 8]) = b1;
    __syncthreads();
    bf16x8 af[4], bfr[4];
#pragma unroll
    for (int i = 0; i < 4; i++)
      af[i] = *(const bf16x8*)(&As[(lq * 128 + wm + i * 16 + lr) * 8]);
#pragma unroll
    for (int j = 0; j < 4; j++)
      bfr[j] = *(const bf16x8*)(&Bs[(lq * 128 + wn + j * 16 + lr) * 8]);
#pragma unroll
    for (int i = 0; i < 4; i++)
#pragma unroll
      for (int j = 0; j < 4; j++)
        acc[i][j] = __builtin_amdgcn_mfma_f32_16x16x32_bf16(af[i], bfr[j], acc[i][j], 0, 0, 0);
  }

  // epilogue: C/D layout col=lane&15, row=(lane>>4)*4+reg (m89/m91 verified)
  bf16* Cg = g.C + (long long)bz * g.Cb;
#pragma unroll
  for (int i = 0; i < 4; i++) {
#pragma unroll
    for (int v = 0; v < 4; v++) {
      int row = by * 128 + wm + i * 16 + lq * 4 + v;
      float srow = 0.f;
      if (EPI == 1) srow = g.s1[bz * g.L + row] + g.abp[0];
#pragma unroll
      for (int j = 0; j < 4; j++) {
        int col = bx * 128 + wn + j * 16 + lr;
        float val = acc[i][j][v];
        if (EPI == 0) val += g.bias[col];
        if (EPI == 1) { val += srow + g.s2[bz * g.L + col]; val = fmaxf(val, 0.f); }
        if (EPI == 3) { val += g.bias[col]; val = 1.f / (1.f + __expf(-val)); }
        Cg[(long long)row * g.ldc + col] = (bf16)val;
      }
    }
  }
}

// weights prep: w1T[l][n][k] = [tW|cW]^T (bf16), w2T[n][k] = [ffW|frW]^T,
// bias1[l][n] = [tb|cb], bias2[n] = [ffb|frb]
__global__ void wprep(const float* tW, const float* tb, const float* cW, const float* cb,
                      const float* frW, const float* frb, const float* ffW, const float* ffb,
                      bf16* w1T, bf16* w2T, float* bias1, float* bias2) {
  int idx = blockIdx.x * 256 + threadIdx.x;
  const int N1 = 1048576, N2 = 1048576;   // 2*1024*512, 1024*1024
  if (idx < N1) {
    int l = idx >> 19;
    int rem = idx & 524287;
    int n = rem >> 9, k = rem & 511;
    float v = (n < 512) ? tW[l * 262144 + k * 512 + n]
                        : cW[l * 262144 + k * 512 + (n - 512)];
    w1T[idx] = (bf16)v;
  } else if (idx < N1 + N2) {
    int j = idx - N1;
    int n = j >> 10, k = j & 1023;
    float v = (n < 512) ? ffW[k * 512 + n] : frW[k * 512 + (n - 512)];
    w2T[j] = (bf16)v;
  } else if (idx < N1 + N2 + 3072) {
    int j = idx - (N1 + N2);
    if (j < 2048) {
      int l = j >> 10, n = j & 1023;
      bias1[j] = (n < 512) ? tb[l * 512 + n] : cb[l * 512 + (n - 512)];
    } else {
      int n = j - 2048;
      bias2[n] = (n < 512) ? ffb[n] : frb[n - 512];
    }
  }
}

// inputs(fp32) -> xb(bf16) and left half of cat16
__global__ void init_conv(const float* inp, bf16* xb, bf16* cat16) {
  long long i8 = ((long long)blockIdx.x * 256 + threadIdx.x) * 8;
  int m = (int)(i8 >> 9), u = (int)(i8 & 511);
  bf16x8 o;
#pragma unroll
  for (int k = 0; k < 8; k++) o[k] = (bf16)inp[i8 + k];
  *(bf16x8*)(xb + i8) = o;
  *(bf16x8*)(cat16 + (long long)m * 1024 + u) = o;
}

// highway update: x = relu(pt)*sig(pc) + x*(1-sig(pc)); writes fp32 + bf16
__global__ void highway_ew(const bf16* pre, const float* xin, float* xout, bf16* xb) {
  long long i8 = ((long long)blockIdx.x * 256 + threadIdx.x) * 8;
  int m = (int)(i8 >> 9), u = (int)(i8 & 511);
  bf16x8 t8 = *(const bf16x8*)(pre + (long long)m * 1024 + u);
  bf16x8 c8 = *(const bf16x8*)(pre + (long long)m * 1024 + 512 + u);
  bf16x8 o;
#pragma unroll
  for (int k = 0; k < 8; k++) {
    float t = fmaxf((float)t8[k], 0.f);
    float c = 1.f / (1.f + __expf(-(float)c8[k]));
    float x = xin[i8 + k];
    float xn = t * c + x * (1.f - c);
    xout[i8 + k] = xn;
    o[k] = (bf16)xn;
  }
  *(bf16x8*)(xb + i8) = o;
}

// s1[m] = x[m,:].w1, s2[m] = x[m,:].w2 — one wave per row
__global__ void s1s2_k(const bf16* xb, const float* aW, float* s1, float* s2) {
  int wid = threadIdx.x >> 6, lane = threadIdx.x & 63;
  int m = blockIdx.x * 4 + wid;
  const bf16* row = xb + (long long)m * 512;
  float a1 = 0.f, a2 = 0.f;
#pragma unroll
  for (int i = 0; i < 8; i++) {
    int d = lane + i * 64;
    float x = (float)row[d];
    a1 += x * aW[d];
    a2 += x * aW[512 + d];
  }
  for (int off = 32; off; off >>= 1) {
    a1 += __shfl_down(a1, off, 64);
    a2 += __shfl_down(a2, off, 64);
  }
  if (!lane) { s1[m] = a1; s2[m] = a2; }
}

// q = x * w3 (bf16)
__global__ void q16_k(const bf16* xb, const float* w3, bf16* q16) {
  long long i8 = ((long long)blockIdx.x * 256 + threadIdx.x) * 8;
  int d = (int)(i8 & 511);
  bf16x8 xv = *(const bf16x8*)(xb + i8);
  bf16x8 o;
#pragma unroll
  for (int k = 0; k < 8; k++) o[k] = (bf16)((float)xv[k] * w3[d + k]);
  *(bf16x8*)(q16 + i8) = o;
}

// per-batch transpose: xT[b][d][j] = x[b][j][d]
__global__ __launch_bounds__(256) void transpose_k(const bf16* xb, bf16* xT) {
  __shared__ bf16 t[64][65];
  int b = blockIdx.z;
  int d0 = blockIdx.x * 64, j0 = blockIdx.y * 64;
  const bf16* src = xb + (long long)b * 524288;
  bf16* dst = xT + (long long)b * 524288;
  int tid = threadIdx.x;
  int rr = tid >> 3, cc = (tid & 7) * 8;
#pragma unroll
  for (int it = 0; it < 2; ++it) {
    int r = rr + it * 32;
    bf16x8 v = *(const bf16x8*)(src + (long long)(j0 + r) * 512 + d0 + cc);
#pragma unroll
    for (int k = 0; k < 8; k++) t[cc + k][r] = v[k];
  }
  __syncthreads();
#pragma unroll
  for (int it = 0; it < 2; ++it) {
    int r = rr + it * 32;
    bf16x8 v;
#pragma unroll
    for (int k = 0; k < 8; k++) v[k] = t[r][cc + k];
    *(bf16x8*)(dst + (long long)(d0 + r) * 1024 + j0 + cc) = v;
  }
}

// in-place softmax over rows of 1024 (S already relu'd, bf16)
__global__ __launch_bounds__(256) void softmax_k(bf16* S) {
  __shared__ float red[8];
  long long base = (long long)blockIdx.x * 1024;
  int tid = threadIdx.x, lane = tid & 63, wid = tid >> 6;
  float v[4];
#pragma unroll
  for (int i = 0; i < 4; i++) v[i] = (float)S[base + tid + 256 * i];
  float m = fmaxf(fmaxf(v[0], v[1]), fmaxf(v[2], v[3]));
  for (int off = 32; off; off >>= 1) m = fmaxf(m, __shfl_down(m, off, 64));
  if (!lane) red[wid] = m;
  __syncthreads();
  m = fmaxf(fmaxf(red[0], red[1]), fmaxf(red[2], red[3]));
  float e[4], s = 0.f;
#pragma unroll
  for (int i = 0; i < 4; i++) { e[i] = __expf(v[i] - m); s += e[i]; }
  for (int off = 32; off; off >>= 1) s += __shfl_down(s, off, 64);
  if (!lane) red[4 + wid] = s;
  __syncthreads();
  float inv = 1.f / (red[4] + red[5] + red[6] + red[7]);
#pragma unroll
  for (int i = 0; i < 4; i++) S[base + tid + 256 * i] = (bf16)(e[i] * inv);
}

// out = sigmoid(pre_r)*inputs + sigmoid(pre_z)^2 (pre already sigmoided) — fp32 out
__global__ void final_out(const bf16* pre, const float* inp, float* out) {
  long long i8 = ((long long)blockIdx.x * 256 + threadIdx.x) * 8;
  int m = (int)(i8 >> 9), u = (int)(i8 & 511);
  bf16x8 z8 = *(const bf16x8*)(pre + (long long)m * 1024 + u);
  bf16x8 r8 = *(const bf16x8*)(pre + (long long)m * 1024 + 512 + u);
  f32x4 o0, o1;
#pragma unroll
  for (int k = 0; k < 8; k++) {
    float z = (float)z8[k], r = (float)r8[k];
    float x = inp[i8 + k];
    float val = r * x + z * z;
    if (k < 4) o0[k] = val; else o1[k - 4] = val;
  }
  *(f32x4*)(out + i8) = o0;
  *(f32x4*)(out + i8 + 4) = o1;
}

extern "C" void kernel_launch(void* const* d_in, const int* in_sizes, int n_in,
                              void* d_out, int out_size, void* d_ws, size_t ws_size,
                              hipStream_t stream) {
  const float* inp = (const float*)d_in[0];
  const float* tW  = (const float*)d_in[1];
  const float* tb  = (const float*)d_in[2];
  const float* cW  = (const float*)d_in[3];
  const float* cb  = (const float*)d_in[4];
  const float* aW  = (const float*)d_in[5];
  const float* ab  = (const float*)d_in[6];
  const float* frW = (const float*)d_in[7];
  const float* frb = (const float*)d_in[8];
  const float* ffW = (const float*)d_in[9];
  const float* ffb = (const float*)d_in[10];
  float* out = (float*)d_out;

  char* p = (char*)d_ws;
  auto alloc = [&](size_t bytes) { char* r = p; p += (bytes + 255) & ~size_t(255); return r; };
  float* x32  = (float*)alloc(33554432);   // fp32 running x
  bf16* xb    = (bf16*) alloc(16777216);   // bf16 running x
  bf16* q16   = (bf16*) alloc(16777216);   // x * w3
  bf16* xT16  = (bf16*) alloc(16777216);   // per-batch x^T
  bf16* cat16 = (bf16*) alloc(33554432);   // [inputs | att] bf16
  bf16* preS  = (bf16*) alloc(33554432);   // shared: highway pre / scores / final pre
  float* s1   = (float*)alloc(65536);
  float* s2   = (float*)alloc(65536);
  bf16* w1T   = (bf16*) alloc(2097152);    // [tW|cW]^T per layer
  bf16* w2T   = (bf16*) alloc(2097152);    // [ffW|frW]^T
  float* bias1= (float*)alloc(8192);
  float* bias2= (float*)alloc(4096);

  wprep<<<CDIV(1048576 + 1048576 + 3072, 256), 256, 0, stream>>>(
      tW, tb, cW, cb, frW, frb, ffW, ffb, w1T, w2T, bias1, bias2);
  init_conv<<<4096, 256, 0, stream>>>(inp, xb, cat16);

  for (int l = 0; l < 2; l++) {
    GemmArgs g{};
    g.A = xb; g.B = w1T + (long long)l * 524288; g.C = preS;
    g.K = 512; g.lda = 512; g.ldb = 512; g.ldc = 1024;
    g.Ab = g.Bb = g.Cb = 0; g.bias = bias1 + l * 1024;
    gemm_nt<0><<<dim3(8, 128, 1), 256, 0, stream>>>(g);
    highway_ew<<<4096, 256, 0, stream>>>(preS, l == 0 ? inp : x32, x32, xb);
  }

  s1s2_k<<<4096, 256, 0, stream>>>(xb, aW, s1, s2);
  q16_k<<<4096, 256, 0, stream>>>(xb, aW + 1024, q16);
  transpose_k<<<dim3(8, 16, 16), 256, 0, stream>>>(xb, xT16);

  {  // scores: S = relu(Q K^T + s1 + s2 + ab), bf16 into preS
    GemmArgs g{};
    g.A = q16; g.B = xb; g.C = preS;
    g.K = 512; g.lda = 512; g.ldb = 512; g.ldc = 1024;
    g.Ab = 524288; g.Bb = 524288; g.Cb = 1048576;
    g.s1 = s1; g.s2 = s2; g.abp = ab; g.L = 1024;
    gemm_nt<1><<<dim3(8, 8, 16), 256, 0, stream>>>(g);
  }
  softmax_k<<<16384, 256, 0, stream>>>(preS);
  {  // att = P @ x -> right half of cat16
    GemmArgs g{};
    g.A = preS; g.B = xT16; g.C = cat16 + 512;
    g.K = 1024; g.lda = 1024; g.ldb = 1024; g.ldc = 1024;
    g.Ab = 1048576; g.Bb = 524288; g.Cb = 1048576;
    gemm_nt<2><<<dim3(4, 8, 16), 256, 0, stream>>>(g);
  }
  {  // final: sigmoid(cat @ [ffW|frW] + bias) -> preS
    GemmArgs g{};
    g.A = cat16; g.B = w2T; g.C = preS;
    g.K = 1024; g.lda = 1024; g.ldb = 1024; g.ldc = 1024;
    g.Ab = g.Bb = g.Cb = 0; g.bias = bias2;
    gemm_nt<3><<<dim3(8, 128, 1), 256, 0, stream>>>(g);
  }
  final_out<<<4096, 256, 0, stream>>>(preS, inp, out);
}

// Round 4
// 315.934 us; speedup vs baseline: 1.3103x; 1.3103x over previous
//
#include <hip/hip_runtime.h>
#include <math.h>

typedef __bf16 bf16;
typedef __attribute__((ext_vector_type(8))) __bf16 bf16x8;
typedef __attribute__((ext_vector_type(4))) float f32x4;

#define CDIV(a,b) (((a)+(b)-1)/(b))

// ---------------------------------------------------------------------------
// B=16, L=1024, U=512, H=2. M = B*L = 16384. fp32 I/O, bf16 internal GEMMs.
// R4 changes: XCD-aware block swizzle (L2 locality; FETCH was 4x unique data),
// global_load_lds width-16 staging with BK=64, bf16-only running x.
// ---------------------------------------------------------------------------

__device__ __forceinline__ void load_lds16(const bf16* g, bf16* l) {
  __builtin_amdgcn_global_load_lds(
      (const __attribute__((address_space(1))) unsigned int*)(g),
      (__attribute__((address_space(3))) unsigned int*)(l), 16, 0, 0);
}

struct GemmArgs {
  const bf16* A; const bf16* B; bf16* C;
  int K, lda, ldb, ldc;
  long long Ab, Bb, Cb;          // batch strides in elements
  const float* bias;             // EPI 0 / 3
  const float* s1; const float* s2; const float* abp; // EPI 1
  int L;
  int gxsh, gysh;                // log2(GX), log2(GY)
};

// NT GEMM: C[M,N] = A[M,K] @ Bt[N,K]^T, bf16 in, fp32 accum.
// Tile 128x128, BK=64, 256 threads = 4 waves (2x2), each wave 64x64 via
// 4x4 mfma_f32_16x16x32_bf16.
// Staging: __builtin_amdgcn_global_load_lds width=16. LDS layout: 16B granule
// p = row*8 + (kc ^ (row&7))  (XOR swizzle folded into the global address each
// lane fetches -> conflict-equalized reads, HW-contiguous writes).
// Block swizzle: xcd = bid&7; each XCD owns a contiguous slab of (z,y) tiles
// covering all x tiles (x fastest) -> per-XCD L2 working set 2-6 MB.
template<int EPI>
__global__ __launch_bounds__(256, 4)
void gemm_nt(GemmArgs g) {
  __shared__ bf16 As[128 * 64];
  __shared__ bf16 Bs[128 * 64];
  const int tid = threadIdx.x;

  // XCD-aware swizzled block mapping
  const int bid = blockIdx.x;
  const int xcd = bid & 7;
  const int t = bid >> 3;
  const int bx = t & ((1 << g.gxsh) - 1);
  const int r  = t >> g.gxsh;
  const int Rx = gridDim.x >> (3 + g.gxsh);      // (z,y)-rows per XCD
  const int gr = xcd * Rx + r;
  const int by = gr & ((1 << g.gysh) - 1);
  const int bz = gr >> g.gysh;

  const bf16* Ag = g.A + (long long)bz * g.Ab + (long long)(by * 128) * g.lda;
  const bf16* Bg = g.B + (long long)bz * g.Bb + (long long)(bx * 128) * g.ldb;
  const int wid = tid >> 6, lane = tid & 63;
  const int wm = (wid >> 1) << 6;      // wave row offset 0/64
  const int wn = (wid & 1) << 6;       // wave col offset 0/64
  const int lr = lane & 15, lq = lane >> 4;

  f32x4 acc[4][4];
#pragma unroll
  for (int i = 0; i < 4; i++)
#pragma unroll
    for (int j = 0; j < 4; j++) acc[i][j] = f32x4{0.f, 0.f, 0.f, 0.f};

  // staging coords (per global_load_lds inst): chunk ci covers rows ci*8..+7
  const int srow8 = (tid >> 3) & 7;              // lane>>3
  const int skc   = (tid & 7) ^ srow8;           // XOR-swizzled k-chunk
  const int lswz  = (lr & 7);

  for (int k0 = 0; k0 < g.K; k0 += 64) {
    __syncthreads();                    // prior iter's ds_reads done
#pragma unroll
    for (int j = 0; j < 4; j++) {
      const int ci = (tid >> 6) * 4 + j;
      const int row = ci * 8 + srow8;
      load_lds16(Ag + (long long)row * g.lda + k0 + skc * 8, As + ci * 512);
      load_lds16(Bg + (long long)row * g.ldb + k0 + skc * 8, Bs + ci * 512);
    }
    __syncthreads();                    // drains vmcnt (compiler-inserted)
#pragma unroll
    for (int ks = 0; ks < 2; ks++) {
      bf16x8 af[4], bfr[4];
      const int kx = (ks * 4 + lq) ^ lswz;
#pragma unroll
      for (int i = 0; i < 4; i++)
        af[i] = *(const bf16x8*)(&As[(wm + i * 16 + lr) * 64 + kx * 8]);
#pragma unroll
      for (int j = 0; j < 4; j++)
        bfr[j] = *(const bf16x8*)(&Bs[(wn + j * 16 + lr) * 64 + kx * 8]);
#pragma unroll
      for (int i = 0; i < 4; i++)
#pragma unroll
        for (int j = 0; j < 4; j++)
          acc[i][j] = __builtin_amdgcn_mfma_f32_16x16x32_bf16(af[i], bfr[j], acc[i][j], 0, 0, 0);
    }
  }

  // epilogue: C/D layout col=lane&15, row=(lane>>4)*4+reg (m89/m91 verified)
  bf16* Cg = g.C + (long long)bz * g.Cb;
#pragma unroll
  for (int i = 0; i < 4; i++) {
#pragma unroll
    for (int v = 0; v < 4; v++) {
      int row = by * 128 + wm + i * 16 + lq * 4 + v;
      float srow = 0.f;
      if (EPI == 1) srow = g.s1[bz * g.L + row] + g.abp[0];
#pragma unroll
      for (int j = 0; j < 4; j++) {
        int col = bx * 128 + wn + j * 16 + lr;
        float val = acc[i][j][v];
        if (EPI == 0) val += g.bias[col];
        if (EPI == 1) { val += srow + g.s2[bz * g.L + col]; val = fmaxf(val, 0.f); }
        if (EPI == 3) { val += g.bias[col]; val = 1.f / (1.f + __expf(-val)); }
        Cg[(long long)row * g.ldc + col] = (bf16)val;
      }
    }
  }
}

// weights prep: w1T[l][n][k] = [tW|cW]^T (bf16), w2T[n][k] = [ffW|frW]^T,
// bias1[l][n] = [tb|cb], bias2[n] = [ffb|frb]
__global__ void wprep(const float* tW, const float* tb, const float* cW, const float* cb,
                      const float* frW, const float* frb, const float* ffW, const float* ffb,
                      bf16* w1T, bf16* w2T, float* bias1, float* bias2) {
  int idx = blockIdx.x * 256 + threadIdx.x;
  const int N1 = 1048576, N2 = 1048576;   // 2*1024*512, 1024*1024
  if (idx < N1) {
    int l = idx >> 19;
    int rem = idx & 524287;
    int n = rem >> 9, k = rem & 511;
    float v = (n < 512) ? tW[l * 262144 + k * 512 + n]
                        : cW[l * 262144 + k * 512 + (n - 512)];
    w1T[idx] = (bf16)v;
  } else if (idx < N1 + N2) {
    int j = idx - N1;
    int n = j >> 10, k = j & 1023;
    float v = (n < 512) ? ffW[k * 512 + n] : frW[k * 512 + (n - 512)];
    w2T[j] = (bf16)v;
  } else if (idx < N1 + N2 + 3072) {
    int j = idx - (N1 + N2);
    if (j < 2048) {
      int l = j >> 10, n = j & 1023;
      bias1[j] = (n < 512) ? tb[l * 512 + n] : cb[l * 512 + (n - 512)];
    } else {
      int n = j - 2048;
      bias2[n] = (n < 512) ? ffb[n] : frb[n - 512];
    }
  }
}

// inputs(fp32) -> xb(bf16) and left half of cat16
__global__ void init_conv(const float* inp, bf16* xb, bf16* cat16) {
  long long i8 = ((long long)blockIdx.x * 256 + threadIdx.x) * 8;
  int m = (int)(i8 >> 9), u = (int)(i8 & 511);
  bf16x8 o;
#pragma unroll
  for (int k = 0; k < 8; k++) o[k] = (bf16)inp[i8 + k];
  *(bf16x8*)(xb + i8) = o;
  *(bf16x8*)(cat16 + (long long)m * 1024 + u) = o;
}

// highway update: x = relu(pt)*sig(pc) + x*(1-sig(pc)); bf16 in/out (in-place ok)
__global__ void highway_ew(const bf16* pre, const bf16* xin, bf16* xout) {
  long long i8 = ((long long)blockIdx.x * 256 + threadIdx.x) * 8;
  int m = (int)(i8 >> 9), u = (int)(i8 & 511);
  bf16x8 t8 = *(const bf16x8*)(pre + (long long)m * 1024 + u);
  bf16x8 c8 = *(const bf16x8*)(pre + (long long)m * 1024 + 512 + u);
  bf16x8 x8 = *(const bf16x8*)(xin + i8);
  bf16x8 o;
#pragma unroll
  for (int k = 0; k < 8; k++) {
    float t = fmaxf((float)t8[k], 0.f);
    float c = 1.f / (1.f + __expf(-(float)c8[k]));
    float x = (float)x8[k];
    o[k] = (bf16)(t * c + x * (1.f - c));
  }
  *(bf16x8*)(xout + i8) = o;
}

// s1[m] = x[m,:].w1, s2[m] = x[m,:].w2 — one wave per row
__global__ void s1s2_k(const bf16* xb, const float* aW, float* s1, float* s2) {
  int wid = threadIdx.x >> 6, lane = threadIdx.x & 63;
  int m = blockIdx.x * 4 + wid;
  const bf16* row = xb + (long long)m * 512;
  float a1 = 0.f, a2 = 0.f;
#pragma unroll
  for (int i = 0; i < 8; i++) {
    int d = lane + i * 64;
    float x = (float)row[d];
    a1 += x * aW[d];
    a2 += x * aW[512 + d];
  }
  for (int off = 32; off; off >>= 1) {
    a1 += __shfl_down(a1, off, 64);
    a2 += __shfl_down(a2, off, 64);
  }
  if (!lane) { s1[m] = a1; s2[m] = a2; }
}

// q = x * w3 (bf16)
__global__ void q16_k(const bf16* xb, const float* w3, bf16* q16) {
  long long i8 = ((long long)blockIdx.x * 256 + threadIdx.x) * 8;
  int d = (int)(i8 & 511);
  bf16x8 xv = *(const bf16x8*)(xb + i8);
  bf16x8 o;
#pragma unroll
  for (int k = 0; k < 8; k++) o[k] = (bf16)((float)xv[k] * w3[d + k]);
  *(bf16x8*)(q16 + i8) = o;
}

// per-batch transpose: xT[b][d][j] = x[b][j][d]
__global__ __launch_bounds__(256) void transpose_k(const bf16* xb, bf16* xT) {
  __shared__ bf16 t[64][65];
  int b = blockIdx.z;
  int d0 = blockIdx.x * 64, j0 = blockIdx.y * 64;
  const bf16* src = xb + (long long)b * 524288;
  bf16* dst = xT + (long long)b * 524288;
  int tid = threadIdx.x;
  int rr = tid >> 3, cc = (tid & 7) * 8;
#pragma unroll
  for (int it = 0; it < 2; ++it) {
    int r = rr + it * 32;
    bf16x8 v = *(const bf16x8*)(src + (long long)(j0 + r) * 512 + d0 + cc);
#pragma unroll
    for (int k = 0; k < 8; k++) t[cc + k][r] = v[k];
  }
  __syncthreads();
#pragma unroll
  for (int it = 0; it < 2; ++it) {
    int r = rr + it * 32;
    bf16x8 v;
#pragma unroll
    for (int k = 0; k < 8; k++) v[k] = t[r][cc + k];
    *(bf16x8*)(dst + (long long)(d0 + r) * 1024 + j0 + cc) = v;
  }
}

// in-place softmax over rows of 1024 (S already relu'd, bf16)
__global__ __launch_bounds__(256) void softmax_k(bf16* S) {
  __shared__ float red[8];
  long long base = (long long)blockIdx.x * 1024;
  int tid = threadIdx.x, lane = tid & 63, wid = tid >> 6;
  float v[4];
#pragma unroll
  for (int i = 0; i < 4; i++) v[i] = (float)S[base + tid + 256 * i];
  float m = fmaxf(fmaxf(v[0], v[1]), fmaxf(v[2], v[3]));
  for (int off = 32; off; off >>= 1) m = fmaxf(m, __shfl_down(m, off, 64));
  if (!lane) red[wid] = m;
  __syncthreads();
  m = fmaxf(fmaxf(red[0], red[1]), fmaxf(red[2], red[3]));
  float e[4], s = 0.f;
#pragma unroll
  for (int i = 0; i < 4; i++) { e[i] = __expf(v[i] - m); s += e[i]; }
  for (int off = 32; off; off >>= 1) s += __shfl_down(s, off, 64);
  if (!lane) red[4 + wid] = s;
  __syncthreads();
  float inv = 1.f / (red[4] + red[5] + red[6] + red[7]);
#pragma unroll
  for (int i = 0; i < 4; i++) S[base + tid + 256 * i] = (bf16)(e[i] * inv);
}

// out = sigmoid(pre_r)*inputs + sigmoid(pre_z)^2 (pre already sigmoided) — fp32 out
__global__ void final_out(const bf16* pre, const float* inp, float* out) {
  long long i8 = ((long long)blockIdx.x * 256 + threadIdx.x) * 8;
  int m = (int)(i8 >> 9), u = (int)(i8 & 511);
  bf16x8 z8 = *(const bf16x8*)(pre + (long long)m * 1024 + u);
  bf16x8 r8 = *(const bf16x8*)(pre + (long long)m * 1024 + 512 + u);
  f32x4 o0, o1;
#pragma unroll
  for (int k = 0; k < 8; k++) {
    float z = (float)z8[k], r = (float)r8[k];
    float x = inp[i8 + k];
    float val = r * x + z * z;
    if (k < 4) o0[k] = val; else o1[k - 4] = val;
  }
  *(f32x4*)(out + i8) = o0;
  *(f32x4*)(out + i8 + 4) = o1;
}

extern "C" void kernel_launch(void* const* d_in, const int* in_sizes, int n_in,
                              void* d_out, int out_size, void* d_ws, size_t ws_size,
                              hipStream_t stream) {
  const float* inp = (const float*)d_in[0];
  const float* tW  = (const float*)d_in[1];
  const float* tb  = (const float*)d_in[2];
  const float* cW  = (const float*)d_in[3];
  const float* cb  = (const float*)d_in[4];
  const float* aW  = (const float*)d_in[5];
  const float* ab  = (const float*)d_in[6];
  const float* frW = (const float*)d_in[7];
  const float* frb = (const float*)d_in[8];
  const float* ffW = (const float*)d_in[9];
  const float* ffb = (const float*)d_in[10];
  float* out = (float*)d_out;

  char* p = (char*)d_ws;
  auto alloc = [&](size_t bytes) { char* r = p; p += (bytes + 255) & ~size_t(255); return r; };
  bf16* xb    = (bf16*) alloc(16777216);   // bf16 running x
  bf16* q16   = (bf16*) alloc(16777216);   // x * w3
  bf16* xT16  = (bf16*) alloc(16777216);   // per-batch x^T
  bf16* cat16 = (bf16*) alloc(33554432);   // [inputs | att] bf16
  bf16* preS  = (bf16*) alloc(33554432);   // shared: highway pre / scores / final pre
  float* s1   = (float*)alloc(65536);
  float* s2   = (float*)alloc(65536);
  bf16* w1T   = (bf16*) alloc(2097152);    // [tW|cW]^T per layer
  bf16* w2T   = (bf16*) alloc(2097152);    // [ffW|frW]^T
  float* bias1= (float*)alloc(8192);
  float* bias2= (float*)alloc(4096);

  wprep<<<CDIV(1048576 + 1048576 + 3072, 256), 256, 0, stream>>>(
      tW, tb, cW, cb, frW, frb, ffW, ffb, w1T, w2T, bias1, bias2);
  init_conv<<<4096, 256, 0, stream>>>(inp, xb, cat16);

  for (int l = 0; l < 2; l++) {
    GemmArgs g{};
    g.A = xb; g.B = w1T + (long long)l * 524288; g.C = preS;
    g.K = 512; g.lda = 512; g.ldb = 512; g.ldc = 1024;
    g.Ab = g.Bb = g.Cb = 0; g.bias = bias1 + l * 1024;
    g.gxsh = 3; g.gysh = 7;
    gemm_nt<0><<<1024, 256, 0, stream>>>(g);
    highway_ew<<<4096, 256, 0, stream>>>(preS, xb, xb);
  }

  s1s2_k<<<4096, 256, 0, stream>>>(xb, aW, s1, s2);
  q16_k<<<4096, 256, 0, stream>>>(xb, aW + 1024, q16);
  transpose_k<<<dim3(8, 16, 16), 256, 0, stream>>>(xb, xT16);

  {  // scores: S = relu(Q K^T + s1 + s2 + ab), bf16 into preS
    GemmArgs g{};
    g.A = q16; g.B = xb; g.C = preS;
    g.K = 512; g.lda = 512; g.ldb = 512; g.ldc = 1024;
    g.Ab = 524288; g.Bb = 524288; g.Cb = 1048576;
    g.s1 = s1; g.s2 = s2; g.abp = ab; g.L = 1024;
    g.gxsh = 3; g.gysh = 3;
    gemm_nt<1><<<1024, 256, 0, stream>>>(g);
  }
  softmax_k<<<16384, 256, 0, stream>>>(preS);
  {  // att = P @ x -> right half of cat16
    GemmArgs g{};
    g.A = preS; g.B = xT16; g.C = cat16 + 512;
    g.K = 1024; g.lda = 1024; g.ldb = 1024; g.ldc = 1024;
    g.Ab = 1048576; g.Bb = 524288; g.Cb = 1048576;
    g.gxsh = 2; g.gysh = 3;
    gemm_nt<2><<<512, 256, 0, stream>>>(g);
  }
  {  // final: sigmoid(cat @ [ffW|frW] + bias) -> preS
    GemmArgs g{};
    g.A = cat16; g.B = w2T; g.C = preS;
    g.K = 1024; g.lda = 1024; g.ldb = 1024; g.ldc = 1024;
    g.Ab = g.Bb = g.Cb = 0; g.bias = bias2;
    g.gxsh = 3; g.gysh = 7;
    gemm_nt<3><<<1024, 256, 0, stream>>>(g);
  }
  final_out<<<4096, 256, 0, stream>>>(preS, inp, out);
}

// Round 5
// 291.096 us; speedup vs baseline: 1.4221x; 1.0853x over previous
//
#include <hip/hip_runtime.h>
#include <math.h>

typedef __bf16 bf16;
typedef __attribute__((ext_vector_type(8))) __bf16 bf16x8;
typedef __attribute__((ext_vector_type(4))) float f32x4;

#define CDIV(a,b) (((a)+(b)-1)/(b))

// ---------------------------------------------------------------------------
// B=16, L=1024, U=512, H=2. M = B*L = 16384. fp32 I/O, bf16 internal.
// R5: fuse highway gating + final gating into GEMM epilogues via dual-column
// tiles (t/c resp. z/r for col n = weight rows n / n+512); kill preS bounce
// for 3 of 4 GEMM uses; fuse s1/s2/q into one pass.
// ---------------------------------------------------------------------------

__device__ __forceinline__ void load_lds16(const bf16* g, bf16* l) {
  __builtin_amdgcn_global_load_lds(
      (const __attribute__((address_space(1))) unsigned int*)(g),
      (__attribute__((address_space(3))) unsigned int*)(l), 16, 0, 0);
}

// ============================ plain NT GEMM ================================
struct GemmArgs {
  const bf16* A; const bf16* B; bf16* C;
  int K, lda, ldb, ldc;
  long long Ab, Bb, Cb;
  const float* s1; const float* s2; const float* abp; // EPI 1
  int L;
  int gxsh, gysh;                // log2 tiles in x / y
};

// C[M,N] = A[M,K] @ Bt[N,K]^T. Tile 128x128, BK=64, 4 waves 2x2, 4x4 MFMA
// 16x16x32. global_load_lds w=16; XOR-swizzled k-granules (R4-verified, 0 bank
// conflicts). XCD-aware block swizzle (R4-verified, FETCH 132->25 MB).
template<int EPI>   // 1 = scores (s1+s2+ab, relu), 2 = plain store
__global__ __launch_bounds__(256, 4)
void gemm_nt(GemmArgs g) {
  __shared__ bf16 As[128 * 64];
  __shared__ bf16 Bs[128 * 64];
  const int tid = threadIdx.x;
  const int bid = blockIdx.x;
  const int xcd = bid & 7;
  const int t = bid >> 3;
  const int bx = t & ((1 << g.gxsh) - 1);
  const int r  = t >> g.gxsh;
  const int Rx = gridDim.x >> (3 + g.gxsh);
  const int gr = xcd * Rx + r;
  const int by = gr & ((1 << g.gysh) - 1);
  const int bz = gr >> g.gysh;

  const bf16* Ag = g.A + (long long)bz * g.Ab + (long long)(by * 128) * g.lda;
  const bf16* Bg = g.B + (long long)bz * g.Bb + (long long)(bx * 128) * g.ldb;
  const int wid = tid >> 6, lane = tid & 63;
  const int wm = (wid >> 1) << 6;
  const int wn = (wid & 1) << 6;
  const int lr = lane & 15, lq = lane >> 4;

  f32x4 acc[4][4];
#pragma unroll
  for (int i = 0; i < 4; i++)
#pragma unroll
    for (int j = 0; j < 4; j++) acc[i][j] = f32x4{0.f, 0.f, 0.f, 0.f};

  const int srow8 = (tid >> 3) & 7;
  const int skc   = (tid & 7) ^ srow8;
  const int lswz  = (lr & 7);

  for (int k0 = 0; k0 < g.K; k0 += 64) {
    __syncthreads();
#pragma unroll
    for (int j = 0; j < 4; j++) {
      const int ci = (tid >> 6) * 4 + j;
      const int row = ci * 8 + srow8;
      load_lds16(Ag + (long long)row * g.lda + k0 + skc * 8, As + ci * 512);
      load_lds16(Bg + (long long)row * g.ldb + k0 + skc * 8, Bs + ci * 512);
    }
    __syncthreads();
#pragma unroll
    for (int ks = 0; ks < 2; ks++) {
      bf16x8 af[4], bfr[4];
      const int kx = (ks * 4 + lq) ^ lswz;
#pragma unroll
      for (int i = 0; i < 4; i++)
        af[i] = *(const bf16x8*)(&As[(wm + i * 16 + lr) * 64 + kx * 8]);
#pragma unroll
      for (int j = 0; j < 4; j++)
        bfr[j] = *(const bf16x8*)(&Bs[(wn + j * 16 + lr) * 64 + kx * 8]);
#pragma unroll
      for (int i = 0; i < 4; i++)
#pragma unroll
        for (int j = 0; j < 4; j++)
          acc[i][j] = __builtin_amdgcn_mfma_f32_16x16x32_bf16(af[i], bfr[j], acc[i][j], 0, 0, 0);
    }
  }

  bf16* Cg = g.C + (long long)bz * g.Cb;
#pragma unroll
  for (int i = 0; i < 4; i++) {
#pragma unroll
    for (int v = 0; v < 4; v++) {
      int row = by * 128 + wm + i * 16 + lq * 4 + v;
      float srow = 0.f;
      if (EPI == 1) srow = g.s1[bz * g.L + row] + g.abp[0];
#pragma unroll
      for (int j = 0; j < 4; j++) {
        int col = bx * 128 + wn + j * 16 + lr;
        float val = acc[i][j][v];
        if (EPI == 1) { val += srow + g.s2[bz * g.L + col]; val = fmaxf(val, 0.f); }
        Cg[(long long)row * g.ldc + col] = (bf16)val;
      }
    }
  }
}

// ===================== dual-column fused-gating GEMM =======================
// Output cols n in [0,512); needs weight rows n (t/z) and n+512 (c/r).
// Block: 128 rows x 64 unique cols. B LDS rows bn: grp=bn>>5 -> half=grp&1
// (0=t,1=c), colgrp=grp>>1; global row = half*512 + bx*64 + colgrp*32 + (bn&31).
// Inner loop identical to gemm_nt; acc[i][j] j<2 = t-half, j>=2 = c-half of the
// SAME columns. Epilogue fuses the gate.
struct DualArgs {
  const bf16* A; const bf16* A2;   // A2 = rows for k>=512 (final); else == A
  const bf16* Bt;
  void* C; const void* xres;
  const float* bias_t; const float* bias_c;
  int K, ldb;
};

template<int EPI>   // 0 = highway (bf16 out, bf16 residual), 1 = final (f32)
__global__ __launch_bounds__(256, 4)
void gemm_dual(DualArgs g) {
  __shared__ bf16 As[128 * 64];
  __shared__ bf16 Bs[128 * 64];
  const int tid = threadIdx.x;
  const int bid = blockIdx.x;
  const int xcd = bid & 7;
  const int t = bid >> 3;
  const int bx = t & 7;            // 8 x-tiles (512/64)
  const int r  = t >> 3;
  const int Rx = gridDim.x >> 6;   // 1024/64 = 16 rows per XCD
  const int by = xcd * Rx + r;     // 0..127

  const int wid = tid >> 6, lane = tid & 63;
  const int wm = (wid >> 1) << 6;
  const int wn = (wid & 1) << 6;
  const int lr = lane & 15, lq = lane >> 4;

  f32x4 acc[4][4];
#pragma unroll
  for (int i = 0; i < 4; i++)
#pragma unroll
    for (int j = 0; j < 4; j++) acc[i][j] = f32x4{0.f, 0.f, 0.f, 0.f};

  const int srow8 = (tid >> 3) & 7;
  const int skc   = (tid & 7) ^ srow8;
  const int lswz  = (lr & 7);
  const long long abase = (long long)(by * 128) * 512;

  for (int k0 = 0; k0 < g.K; k0 += 64) {
    const bf16* Ak = (k0 < 512) ? g.A : g.A2;
    const int kk = k0 & 511;
    __syncthreads();
#pragma unroll
    for (int j = 0; j < 4; j++) {
      const int ci = (tid >> 6) * 4 + j;
      const int bn = ci * 8 + srow8;
      load_lds16(Ak + abase + (long long)bn * 512 + kk + skc * 8, As + ci * 512);
      const int grp = bn >> 5, r5 = bn & 31;
      const int grow = ((grp & 1) << 9) + bx * 64 + ((grp >> 1) << 5) + r5;
      load_lds16(g.Bt + (long long)grow * g.ldb + k0 + skc * 8, Bs + ci * 512);
    }
    __syncthreads();
#pragma unroll
    for (int ks = 0; ks < 2; ks++) {
      bf16x8 af[4], bfr[4];
      const int kx = (ks * 4 + lq) ^ lswz;
#pragma unroll
      for (int i = 0; i < 4; i++)
        af[i] = *(const bf16x8*)(&As[(wm + i * 16 + lr) * 64 + kx * 8]);
#pragma unroll
      for (int j = 0; j < 4; j++)
        bfr[j] = *(const bf16x8*)(&Bs[(wn + j * 16 + lr) * 64 + kx * 8]);
#pragma unroll
      for (int i = 0; i < 4; i++)
#pragma unroll
        for (int j = 0; j < 4; j++)
          acc[i][j] = __builtin_amdgcn_mfma_f32_16x16x32_bf16(af[i], bfr[j], acc[i][j], 0, 0, 0);
    }
  }

  // acc[i][j] (j<2): t/z for cols colb+j*16+lr; acc[i][j+2]: c/r same cols.
  const int colb = bx * 64 + (wn >> 1);
#pragma unroll
  for (int i = 0; i < 4; i++) {
#pragma unroll
    for (int v = 0; v < 4; v++) {
      int row = by * 128 + wm + i * 16 + lq * 4 + v;
#pragma unroll
      for (int j = 0; j < 2; j++) {
        int col = colb + j * 16 + lr;
        long long idx = (long long)row * 512 + col;
        float p0 = acc[i][j][v] + g.bias_t[col];
        float p1 = acc[i][j + 2][v] + g.bias_c[col];
        if (EPI == 0) {
          float tt = fmaxf(p0, 0.f);
          float c = 1.f / (1.f + __expf(-p1));
          float x = (float)((const bf16*)g.xres)[idx];
          ((bf16*)g.C)[idx] = (bf16)(tt * c + x * (1.f - c));
        } else {
          float z = 1.f / (1.f + __expf(-p0));
          float rr = 1.f / (1.f + __expf(-p1));
          float x = ((const float*)g.xres)[idx];
          ((float*)g.C)[idx] = rr * x + z * z;
        }
      }
    }
  }
}

// ============================ small kernels ================================
// w1T[l][n][k] = [tW|cW]^T (bf16), w2T[n][k] = [ffW|frW]^T, biases fp32
__global__ void wprep(const float* tW, const float* tb, const float* cW, const float* cb,
                      const float* frW, const float* frb, const float* ffW, const float* ffb,
                      bf16* w1T, bf16* w2T, float* bias1, float* bias2) {
  int idx = blockIdx.x * 256 + threadIdx.x;
  const int N1 = 1048576, N2 = 1048576;
  if (idx < N1) {
    int l = idx >> 19;
    int rem = idx & 524287;
    int n = rem >> 9, k = rem & 511;
    float v = (n < 512) ? tW[l * 262144 + k * 512 + n]
                        : cW[l * 262144 + k * 512 + (n - 512)];
    w1T[idx] = (bf16)v;
  } else if (idx < N1 + N2) {
    int j = idx - N1;
    int n = j >> 10, k = j & 1023;
    float v = (n < 512) ? ffW[k * 512 + n] : frW[k * 512 + (n - 512)];
    w2T[j] = (bf16)v;
  } else if (idx < N1 + N2 + 3072) {
    int j = idx - (N1 + N2);
    if (j < 2048) {
      int l = j >> 10, n = j & 1023;
      bias1[j] = (n < 512) ? tb[l * 512 + n] : cb[l * 512 + (n - 512)];
    } else {
      int n = j - 2048;
      bias2[n] = (n < 512) ? ffb[n] : frb[n - 512];
    }
  }
}

__global__ void init_conv(const float* inp, bf16* xb0) {
  long long i8 = ((long long)blockIdx.x * 256 + threadIdx.x) * 8;
  bf16x8 o;
#pragma unroll
  for (int k = 0; k < 8; k++) o[k] = (bf16)inp[i8 + k];
  *(bf16x8*)(xb0 + i8) = o;
}

// one pass over x: s1 = x.w1, s2 = x.w2 (wave-per-row), q = x*w3
__global__ void s1s2q_k(const bf16* x, const float* aW, float* s1, float* s2, bf16* q16) {
  int wid = threadIdx.x >> 6, lane = threadIdx.x & 63;
  int m = blockIdx.x * 4 + wid;
  long long base = (long long)m * 512;
  int d0 = lane * 8;
  bf16x8 xv = *(const bf16x8*)(x + base + d0);
  float a1 = 0.f, a2 = 0.f;
  bf16x8 o;
#pragma unroll
  for (int k = 0; k < 8; k++) {
    float xx = (float)xv[k];
    a1 += xx * aW[d0 + k];
    a2 += xx * aW[512 + d0 + k];
    o[k] = (bf16)(xx * aW[1024 + d0 + k]);
  }
  *(bf16x8*)(q16 + base + d0) = o;
  for (int off = 32; off; off >>= 1) {
    a1 += __shfl_down(a1, off, 64);
    a2 += __shfl_down(a2, off, 64);
  }
  if (!lane) { s1[m] = a1; s2[m] = a2; }
}

// per-batch transpose: xT[b][d][j] = x[b][j][d]
__global__ __launch_bounds__(256) void transpose_k(const bf16* xb, bf16* xT) {
  __shared__ bf16 t[64][65];
  int b = blockIdx.z;
  int d0 = blockIdx.x * 64, j0 = blockIdx.y * 64;
  const bf16* src = xb + (long long)b * 524288;
  bf16* dst = xT + (long long)b * 524288;
  int tid = threadIdx.x;
  int rr = tid >> 3, cc = (tid & 7) * 8;
#pragma unroll
  for (int it = 0; it < 2; ++it) {
    int r = rr + it * 32;
    bf16x8 v = *(const bf16x8*)(src + (long long)(j0 + r) * 512 + d0 + cc);
#pragma unroll
    for (int k = 0; k < 8; k++) t[cc + k][r] = v[k];
  }
  __syncthreads();
#pragma unroll
  for (int it = 0; it < 2; ++it) {
    int r = rr + it * 32;
    bf16x8 v;
#pragma unroll
    for (int k = 0; k < 8; k++) v[k] = t[r][cc + k];
    *(bf16x8*)(dst + (long long)(d0 + r) * 1024 + j0 + cc) = v;
  }
}

// in-place softmax over rows of 1024
__global__ __launch_bounds__(256) void softmax_k(bf16* S) {
  __shared__ float red[8];
  long long base = (long long)blockIdx.x * 1024;
  int tid = threadIdx.x, lane = tid & 63, wid = tid >> 6;
  float v[4];
#pragma unroll
  for (int i = 0; i < 4; i++) v[i] = (float)S[base + tid + 256 * i];
  float m = fmaxf(fmaxf(v[0], v[1]), fmaxf(v[2], v[3]));
  for (int off = 32; off; off >>= 1) m = fmaxf(m, __shfl_down(m, off, 64));
  if (!lane) red[wid] = m;
  __syncthreads();
  m = fmaxf(fmaxf(red[0], red[1]), fmaxf(red[2], red[3]));
  float e[4], s = 0.f;
#pragma unroll
  for (int i = 0; i < 4; i++) { e[i] = __expf(v[i] - m); s += e[i]; }
  for (int off = 32; off; off >>= 1) s += __shfl_down(s, off, 64);
  if (!lane) red[4 + wid] = s;
  __syncthreads();
  float inv = 1.f / (red[4] + red[5] + red[6] + red[7]);
#pragma unroll
  for (int i = 0; i < 4; i++) S[base + tid + 256 * i] = (bf16)(e[i] * inv);
}

extern "C" void kernel_launch(void* const* d_in, const int* in_sizes, int n_in,
                              void* d_out, int out_size, void* d_ws, size_t ws_size,
                              hipStream_t stream) {
  const float* inp = (const float*)d_in[0];
  const float* tW  = (const float*)d_in[1];
  const float* tb  = (const float*)d_in[2];
  const float* cW  = (const float*)d_in[3];
  const float* cb  = (const float*)d_in[4];
  const float* aW  = (const float*)d_in[5];
  const float* ab  = (const float*)d_in[6];
  const float* frW = (const float*)d_in[7];
  const float* frb = (const float*)d_in[8];
  const float* ffW = (const float*)d_in[9];
  const float* ffb = (const float*)d_in[10];
  float* out = (float*)d_out;

  char* p = (char*)d_ws;
  auto alloc = [&](size_t bytes) { char* r = p; p += (bytes + 255) & ~size_t(255); return r; };
  bf16* xb0   = (bf16*) alloc(16777216);   // bf16(inputs)
  bf16* x1    = (bf16*) alloc(16777216);   // after layer 1
  bf16* x2    = (bf16*) alloc(16777216);   // after layer 2 (= attention x)
  bf16* q16   = (bf16*) alloc(16777216);   // x * w3
  bf16* xT16  = (bf16*) alloc(16777216);   // per-batch x^T
  bf16* att16 = (bf16*) alloc(16777216);   // attention output
  bf16* preS  = (bf16*) alloc(33554432);   // scores / probs
  float* s1   = (float*)alloc(65536);
  float* s2   = (float*)alloc(65536);
  bf16* w1T   = (bf16*) alloc(2097152);
  bf16* w2T   = (bf16*) alloc(2097152);
  float* bias1= (float*)alloc(8192);
  float* bias2= (float*)alloc(4096);

  wprep<<<CDIV(1048576 + 1048576 + 3072, 256), 256, 0, stream>>>(
      tW, tb, cW, cb, frW, frb, ffW, ffb, w1T, w2T, bias1, bias2);
  init_conv<<<4096, 256, 0, stream>>>(inp, xb0);

  {  // highway layers, fused gating
    const bf16* xin[2] = {xb0, x1};
    bf16* xout[2] = {x1, x2};
    for (int l = 0; l < 2; l++) {
      DualArgs g{};
      g.A = xin[l]; g.A2 = xin[l]; g.Bt = w1T + (long long)l * 524288;
      g.C = xout[l]; g.xres = xin[l];
      g.bias_t = bias1 + l * 1024; g.bias_c = bias1 + l * 1024 + 512;
      g.K = 512; g.ldb = 512;
      gemm_dual<0><<<1024, 256, 0, stream>>>(g);
    }
  }

  s1s2q_k<<<4096, 256, 0, stream>>>(x2, aW, s1, s2, q16);
  transpose_k<<<dim3(8, 16, 16), 256, 0, stream>>>(x2, xT16);

  {  // scores: S = relu(Q K^T + s1 + s2 + ab) -> preS
    GemmArgs g{};
    g.A = q16; g.B = x2; g.C = preS;
    g.K = 512; g.lda = 512; g.ldb = 512; g.ldc = 1024;
    g.Ab = 524288; g.Bb = 524288; g.Cb = 1048576;
    g.s1 = s1; g.s2 = s2; g.abp = ab; g.L = 1024;
    g.gxsh = 3; g.gysh = 3;
    gemm_nt<1><<<1024, 256, 0, stream>>>(g);
  }
  softmax_k<<<16384, 256, 0, stream>>>(preS);
  {  // att = P @ x -> att16
    GemmArgs g{};
    g.A = preS; g.B = xT16; g.C = att16;
    g.K = 1024; g.lda = 1024; g.ldb = 1024; g.ldc = 512;
    g.Ab = 1048576; g.Bb = 524288; g.Cb = 524288;
    g.gxsh = 2; g.gysh = 3;
    gemm_nt<2><<<512, 256, 0, stream>>>(g);
  }
  {  // final: out = r*inp + z*z, z/r = sigmoid([xb0|att] @ [ffW|frW] + b)
    DualArgs g{};
    g.A = xb0; g.A2 = att16; g.Bt = w2T;
    g.C = out; g.xres = inp;
    g.bias_t = bias2; g.bias_c = bias2 + 512;
    g.K = 1024; g.ldb = 1024;
    gemm_dual<1><<<1024, 256, 0, stream>>>(g);
  }
}

// Round 6
// 271.750 us; speedup vs baseline: 1.5233x; 1.0712x over previous
//
#include <hip/hip_runtime.h>
#include <math.h>

typedef __bf16 bf16;
typedef __attribute__((ext_vector_type(8))) __bf16 bf16x8;
typedef __attribute__((ext_vector_type(4))) float f32x4;

#define CDIV(a,b) (((a)+(b)-1)/(b))

// ---------------------------------------------------------------------------
// B=16, L=1024, U=512, H=2. M = 16384. fp32 I/O, bf16 internal.
// R6: softmax eliminated as a kernel — scores epilogue writes E=exp(relu(.))
// + atomic row-sums l[]; PV epilogue multiplies by 1/l. s1/s2/q fused into
// highway-2 epilogue. Scores bounded ~10 => exp safe without max-subtraction
// (clamped at 60 as inf-guard).
// ---------------------------------------------------------------------------

__device__ __forceinline__ void load_lds16(const bf16* g, bf16* l) {
  __builtin_amdgcn_global_load_lds(
      (const __attribute__((address_space(1))) unsigned int*)(g),
      (__attribute__((address_space(3))) unsigned int*)(l), 16, 0, 0);
}

// ============================ plain NT GEMM ================================
struct GemmArgs {
  const bf16* A; const bf16* B; bf16* C;
  int K, lda, ldb, ldc;
  long long Ab, Bb, Cb;
  const float* s1; const float* s2; const float* abp; // EPI1; s1=lsum for EPI4
  float* lsum;                   // EPI 1: row sums of E
  int L;
  int gxsh, gysh;
};

// C[M,N] = A[M,K] @ Bt[N,K]^T. Tile 128x128, BK=64, 4 waves 2x2, 4x4 MFMA
// 16x16x32. global_load_lds w=16, XOR-swizzled granules (0 bank conflicts,
// R4-verified). XCD swizzle keeps per-XCD working set in L2 (R4-verified).
template<int EPI>   // 1 = scores->E + lsum atomics, 4 = PV * (1/l)
__global__ __launch_bounds__(256, 4)
void gemm_nt(GemmArgs g) {
  __shared__ bf16 As[128 * 64];
  __shared__ bf16 Bs[128 * 64];
  const int tid = threadIdx.x;
  const int bid = blockIdx.x;
  const int xcd = bid & 7;
  const int t = bid >> 3;
  const int bx = t & ((1 << g.gxsh) - 1);
  const int r  = t >> g.gxsh;
  const int Rx = gridDim.x >> (3 + g.gxsh);
  const int gr = xcd * Rx + r;
  const int by = gr & ((1 << g.gysh) - 1);
  const int bz = gr >> g.gysh;

  const bf16* Ag = g.A + (long long)bz * g.Ab + (long long)(by * 128) * g.lda;
  const bf16* Bg = g.B + (long long)bz * g.Bb + (long long)(bx * 128) * g.ldb;
  const int wid = tid >> 6, lane = tid & 63;
  const int wm = (wid >> 1) << 6;
  const int wn = (wid & 1) << 6;
  const int lr = lane & 15, lq = lane >> 4;

  f32x4 acc[4][4];
#pragma unroll
  for (int i = 0; i < 4; i++)
#pragma unroll
    for (int j = 0; j < 4; j++) acc[i][j] = f32x4{0.f, 0.f, 0.f, 0.f};

  const int srow8 = (tid >> 3) & 7;
  const int skc   = (tid & 7) ^ srow8;
  const int lswz  = (lr & 7);

  for (int k0 = 0; k0 < g.K; k0 += 64) {
    __syncthreads();
#pragma unroll
    for (int j = 0; j < 4; j++) {
      const int ci = (tid >> 6) * 4 + j;
      const int row = ci * 8 + srow8;
      load_lds16(Ag + (long long)row * g.lda + k0 + skc * 8, As + ci * 512);
      load_lds16(Bg + (long long)row * g.ldb + k0 + skc * 8, Bs + ci * 512);
    }
    __syncthreads();
#pragma unroll
    for (int ks = 0; ks < 2; ks++) {
      bf16x8 af[4], bfr[4];
      const int kx = (ks * 4 + lq) ^ lswz;
#pragma unroll
      for (int i = 0; i < 4; i++)
        af[i] = *(const bf16x8*)(&As[(wm + i * 16 + lr) * 64 + kx * 8]);
#pragma unroll
      for (int j = 0; j < 4; j++)
        bfr[j] = *(const bf16x8*)(&Bs[(wn + j * 16 + lr) * 64 + kx * 8]);
#pragma unroll
      for (int i = 0; i < 4; i++)
#pragma unroll
        for (int j = 0; j < 4; j++)
          acc[i][j] = __builtin_amdgcn_mfma_f32_16x16x32_bf16(af[i], bfr[j], acc[i][j], 0, 0, 0);
    }
  }

  bf16* Cg = g.C + (long long)bz * g.Cb;
#pragma unroll
  for (int i = 0; i < 4; i++) {
#pragma unroll
    for (int v = 0; v < 4; v++) {
      int row = by * 128 + wm + i * 16 + lq * 4 + v;
      float srow = 0.f;
      if (EPI == 1) srow = g.s1[bz * g.L + row] + g.abp[0];
      if (EPI == 4) srow = 1.f / g.s1[bz * g.L + row];   // reciprocal of lsum
      float psum = 0.f;
#pragma unroll
      for (int j = 0; j < 4; j++) {
        int col = bx * 128 + wn + j * 16 + lr;
        float val = acc[i][j][v];
        if (EPI == 1) {
          val += srow + g.s2[bz * g.L + col];
          val = fminf(fmaxf(val, 0.f), 60.f);
          val = __expf(val);
          bf16 eb = (bf16)val;
          psum += (float)eb;
          Cg[(long long)row * g.ldc + col] = eb;
        } else {
          val *= srow;
          Cg[(long long)row * g.ldc + col] = (bf16)val;
        }
      }
      if (EPI == 1) {
        // butterfly over the 16 col-lanes (same row)
        psum += __shfl_xor(psum, 1, 64);
        psum += __shfl_xor(psum, 2, 64);
        psum += __shfl_xor(psum, 4, 64);
        psum += __shfl_xor(psum, 8, 64);
        if (lr == 0) atomicAdd(&g.lsum[bz * g.L + row], psum);
      }
    }
  }
}

// ===================== dual-column fused-gating GEMM =======================
// Output cols n in [0,512); weight rows n (t/z) and n+512 (c/r) interleaved in
// the B tile. acc[i][j] j<2 = t-half, j>=2 = c-half of the same cols.
struct DualArgs {
  const bf16* A; const bf16* A2;   // A2 = rows for k>=512 (final); else == A
  const bf16* Bt;
  void* C; const void* xres;
  const float* bias_t; const float* bias_c;
  int K, ldb;
  const float* aW;                 // EPI 2: attention weights (3*512 fp32)
  float* s1a; float* s2a;          // EPI 2: atomic partial dots
  bf16* q;                         // EPI 2: x * w3
};

template<int EPI>  // 0 = highway, 2 = highway + s1/s2/q fusion, 1 = final f32
__global__ __launch_bounds__(256, 4)
void gemm_dual(DualArgs g) {
  __shared__ bf16 As[128 * 64];
  __shared__ bf16 Bs[128 * 64];
  const int tid = threadIdx.x;
  const int bid = blockIdx.x;
  const int xcd = bid & 7;
  const int t = bid >> 3;
  const int bx = t & 7;
  const int r  = t >> 3;
  const int Rx = gridDim.x >> 6;
  const int by = xcd * Rx + r;

  const int wid = tid >> 6, lane = tid & 63;
  const int wm = (wid >> 1) << 6;
  const int wn = (wid & 1) << 6;
  const int lr = lane & 15, lq = lane >> 4;

  f32x4 acc[4][4];
#pragma unroll
  for (int i = 0; i < 4; i++)
#pragma unroll
    for (int j = 0; j < 4; j++) acc[i][j] = f32x4{0.f, 0.f, 0.f, 0.f};

  const int srow8 = (tid >> 3) & 7;
  const int skc   = (tid & 7) ^ srow8;
  const int lswz  = (lr & 7);
  const long long abase = (long long)(by * 128) * 512;

  for (int k0 = 0; k0 < g.K; k0 += 64) {
    const bf16* Ak = (k0 < 512) ? g.A : g.A2;
    const int kk = k0 & 511;
    __syncthreads();
#pragma unroll
    for (int j = 0; j < 4; j++) {
      const int ci = (tid >> 6) * 4 + j;
      const int bn = ci * 8 + srow8;
      load_lds16(Ak + abase + (long long)bn * 512 + kk + skc * 8, As + ci * 512);
      const int grp = bn >> 5, r5 = bn & 31;
      const int grow = ((grp & 1) << 9) + bx * 64 + ((grp >> 1) << 5) + r5;
      load_lds16(g.Bt + (long long)grow * g.ldb + k0 + skc * 8, Bs + ci * 512);
    }
    __syncthreads();
#pragma unroll
    for (int ks = 0; ks < 2; ks++) {
      bf16x8 af[4], bfr[4];
      const int kx = (ks * 4 + lq) ^ lswz;
#pragma unroll
      for (int i = 0; i < 4; i++)
        af[i] = *(const bf16x8*)(&As[(wm + i * 16 + lr) * 64 + kx * 8]);
#pragma unroll
      for (int j = 0; j < 4; j++)
        bfr[j] = *(const bf16x8*)(&Bs[(wn + j * 16 + lr) * 64 + kx * 8]);
#pragma unroll
      for (int i = 0; i < 4; i++)
#pragma unroll
        for (int j = 0; j < 4; j++)
          acc[i][j] = __builtin_amdgcn_mfma_f32_16x16x32_bf16(af[i], bfr[j], acc[i][j], 0, 0, 0);
    }
  }

  const int colb = bx * 64 + (wn >> 1);
#pragma unroll
  for (int i = 0; i < 4; i++) {
#pragma unroll
    for (int v = 0; v < 4; v++) {
      int row = by * 128 + wm + i * 16 + lq * 4 + v;
      float p1s = 0.f, p2s = 0.f;
#pragma unroll
      for (int j = 0; j < 2; j++) {
        int col = colb + j * 16 + lr;
        long long idx = (long long)row * 512 + col;
        float p0 = acc[i][j][v] + g.bias_t[col];
        float p1 = acc[i][j + 2][v] + g.bias_c[col];
        if (EPI == 1) {
          float z = 1.f / (1.f + __expf(-p0));
          float rr = 1.f / (1.f + __expf(-p1));
          float x = ((const float*)g.xres)[idx];
          ((float*)g.C)[idx] = rr * x + z * z;
        } else {
          float tt = fmaxf(p0, 0.f);
          float c = 1.f / (1.f + __expf(-p1));
          float x = (float)((const bf16*)g.xres)[idx];
          bf16 xn = (bf16)(tt * c + x * (1.f - c));
          ((bf16*)g.C)[idx] = xn;
          if (EPI == 2) {
            float xf = (float)xn;
            p1s += xf * g.aW[col];
            p2s += xf * g.aW[512 + col];
            g.q[idx] = (bf16)(xf * g.aW[1024 + col]);
          }
        }
      }
      if (EPI == 2) {
        p1s += __shfl_xor(p1s, 1, 64);
        p1s += __shfl_xor(p1s, 2, 64);
        p1s += __shfl_xor(p1s, 4, 64);
        p1s += __shfl_xor(p1s, 8, 64);
        p2s += __shfl_xor(p2s, 1, 64);
        p2s += __shfl_xor(p2s, 2, 64);
        p2s += __shfl_xor(p2s, 4, 64);
        p2s += __shfl_xor(p2s, 8, 64);
        if (lr == 0) {
          atomicAdd(&g.s1a[row], p1s);
          atomicAdd(&g.s2a[row], p2s);
        }
      }
    }
  }
}

// ============================ small kernels ================================
__global__ void wprep(const float* tW, const float* tb, const float* cW, const float* cb,
                      const float* frW, const float* frb, const float* ffW, const float* ffb,
                      bf16* w1T, bf16* w2T, float* bias1, float* bias2) {
  int idx = blockIdx.x * 256 + threadIdx.x;
  const int N1 = 1048576, N2 = 1048576;
  if (idx < N1) {
    int l = idx >> 19;
    int rem = idx & 524287;
    int n = rem >> 9, k = rem & 511;
    float v = (n < 512) ? tW[l * 262144 + k * 512 + n]
                        : cW[l * 262144 + k * 512 + (n - 512)];
    w1T[idx] = (bf16)v;
  } else if (idx < N1 + N2) {
    int j = idx - N1;
    int n = j >> 10, k = j & 1023;
    float v = (n < 512) ? ffW[k * 512 + n] : frW[k * 512 + (n - 512)];
    w2T[j] = (bf16)v;
  } else if (idx < N1 + N2 + 3072) {
    int j = idx - (N1 + N2);
    if (j < 2048) {
      int l = j >> 10, n = j & 1023;
      bias1[j] = (n < 512) ? tb[l * 512 + n] : cb[l * 512 + (n - 512)];
    } else {
      int n = j - 2048;
      bias2[n] = (n < 512) ? ffb[n] : frb[n - 512];
    }
  }
}

__global__ void init_conv(const float* inp, bf16* xb0) {
  long long i8 = ((long long)blockIdx.x * 256 + threadIdx.x) * 8;
  bf16x8 o;
#pragma unroll
  for (int k = 0; k < 8; k++) o[k] = (bf16)inp[i8 + k];
  *(bf16x8*)(xb0 + i8) = o;
}

// per-batch transpose: xT[b][d][j] = x[b][j][d]
__global__ __launch_bounds__(256) void transpose_k(const bf16* xb, bf16* xT) {
  __shared__ bf16 t[64][65];
  int b = blockIdx.z;
  int d0 = blockIdx.x * 64, j0 = blockIdx.y * 64;
  const bf16* src = xb + (long long)b * 524288;
  bf16* dst = xT + (long long)b * 524288;
  int tid = threadIdx.x;
  int rr = tid >> 3, cc = (tid & 7) * 8;
#pragma unroll
  for (int it = 0; it < 2; ++it) {
    int r = rr + it * 32;
    bf16x8 v = *(const bf16x8*)(src + (long long)(j0 + r) * 512 + d0 + cc);
#pragma unroll
    for (int k = 0; k < 8; k++) t[cc + k][r] = v[k];
  }
  __syncthreads();
#pragma unroll
  for (int it = 0; it < 2; ++it) {
    int r = rr + it * 32;
    bf16x8 v;
#pragma unroll
    for (int k = 0; k < 8; k++) v[k] = t[r][cc + k];
    *(bf16x8*)(dst + (long long)(d0 + r) * 1024 + j0 + cc) = v;
  }
}

extern "C" void kernel_launch(void* const* d_in, const int* in_sizes, int n_in,
                              void* d_out, int out_size, void* d_ws, size_t ws_size,
                              hipStream_t stream) {
  const float* inp = (const float*)d_in[0];
  const float* tW  = (const float*)d_in[1];
  const float* tb  = (const float*)d_in[2];
  const float* cW  = (const float*)d_in[3];
  const float* cb  = (const float*)d_in[4];
  const float* aW  = (const float*)d_in[5];
  const float* ab  = (const float*)d_in[6];
  const float* frW = (const float*)d_in[7];
  const float* frb = (const float*)d_in[8];
  const float* ffW = (const float*)d_in[9];
  const float* ffb = (const float*)d_in[10];
  float* out = (float*)d_out;

  char* p = (char*)d_ws;
  auto alloc = [&](size_t bytes) { char* r = p; p += (bytes + 255) & ~size_t(255); return r; };
  bf16* xb0   = (bf16*) alloc(16777216);   // bf16(inputs)
  bf16* x1    = (bf16*) alloc(16777216);
  bf16* x2    = (bf16*) alloc(16777216);
  bf16* q16   = (bf16*) alloc(16777216);   // x * w3
  bf16* xT16  = (bf16*) alloc(16777216);
  bf16* att16 = (bf16*) alloc(16777216);
  bf16* E16   = (bf16*) alloc(33554432);   // exp(relu(scores)), unnormalized
  float* sred = (float*)alloc(196608);     // s1 | s2 | lsum (atomic targets)
  bf16* w1T   = (bf16*) alloc(2097152);
  bf16* w2T   = (bf16*) alloc(2097152);
  float* bias1= (float*)alloc(8192);
  float* bias2= (float*)alloc(4096);
  float* s1 = sred, *s2 = sred + 16384, *lsum = sred + 32768;

  hipMemsetAsync(sred, 0, 196608, stream);
  wprep<<<CDIV(1048576 + 1048576 + 3072, 256), 256, 0, stream>>>(
      tW, tb, cW, cb, frW, frb, ffW, ffb, w1T, w2T, bias1, bias2);
  init_conv<<<4096, 256, 0, stream>>>(inp, xb0);

  {  // highway 1
    DualArgs g{};
    g.A = xb0; g.A2 = xb0; g.Bt = w1T;
    g.C = x1; g.xres = xb0;
    g.bias_t = bias1; g.bias_c = bias1 + 512;
    g.K = 512; g.ldb = 512;
    gemm_dual<0><<<1024, 256, 0, stream>>>(g);
  }
  {  // highway 2 + fused s1/s2/q
    DualArgs g{};
    g.A = x1; g.A2 = x1; g.Bt = w1T + 524288;
    g.C = x2; g.xres = x1;
    g.bias_t = bias1 + 1024; g.bias_c = bias1 + 1536;
    g.K = 512; g.ldb = 512;
    g.aW = aW; g.s1a = s1; g.s2a = s2; g.q = q16;
    gemm_dual<2><<<1024, 256, 0, stream>>>(g);
  }

  transpose_k<<<dim3(8, 16, 16), 256, 0, stream>>>(x2, xT16);

  {  // scores: E = exp(relu(Q K^T + s1 + s2 + ab)), row sums into lsum
    GemmArgs g{};
    g.A = q16; g.B = x2; g.C = E16;
    g.K = 512; g.lda = 512; g.ldb = 512; g.ldc = 1024;
    g.Ab = 524288; g.Bb = 524288; g.Cb = 1048576;
    g.s1 = s1; g.s2 = s2; g.abp = ab; g.lsum = lsum; g.L = 1024;
    g.gxsh = 3; g.gysh = 3;
    gemm_nt<1><<<1024, 256, 0, stream>>>(g);
  }
  {  // att = (E @ x) / l -> att16
    GemmArgs g{};
    g.A = E16; g.B = xT16; g.C = att16;
    g.K = 1024; g.lda = 1024; g.ldb = 1024; g.ldc = 512;
    g.Ab = 1048576; g.Bb = 524288; g.Cb = 524288;
    g.s1 = lsum; g.L = 1024;
    g.gxsh = 2; g.gysh = 3;
    gemm_nt<4><<<512, 256, 0, stream>>>(g);
  }
  {  // final: out = r*inp + z*z, z/r = sigmoid([xb0|att] @ [ffW|frW] + b)
    DualArgs g{};
    g.A = xb0; g.A2 = att16; g.Bt = w2T;
    g.C = out; g.xres = inp;
    g.bias_t = bias2; g.bias_c = bias2 + 512;
    g.K = 1024; g.ldb = 1024;
    gemm_dual<1><<<1024, 256, 0, stream>>>(g);
  }
}